// Round 4
// baseline (63.984 us; speedup 1.0000x reference)
//
#include <hip/hip_runtime.h>

#define F_   128
#define H_   16
#define E_   32
#define FG   8     // features per wave
#define BPW  64    // b rows per wave
#define WAVES 4
#define NTHREADS (WAVES * 64)   // 256

typedef float v4f __attribute__((ext_vector_type(4)));

// Wave owns (feature-group f0..f0+7) x (b-range of 64). Lane l -> feature
// f = f0 + (l>>3), e4 = l&7. Per b: one coalesced 1 KB wave store.
// x tile (64 b x 8 f = 2 KB/wave) is bulk-staged through wave-private LDS
// at wave start, so the main loop issues ZERO global reads — pure write
// stream + LDS broadcast reads. No barriers (per-wave LDS region).
__global__ __launch_bounds__(NTHREADS, 4)
void nfe_kernel(const float* __restrict__ x,
                const float* __restrict__ W1,
                const float* __restrict__ b1,
                const float* __restrict__ W2,
                const float* __restrict__ b2,
                float* __restrict__ out)
{
    __shared__ float xs[WAVES][BPW * FG];   // 4 x 2 KB = 8 KB

    const int tid  = threadIdx.x;
    const int wave = tid >> 6;
    const int lane = tid & 63;

    const int f0 = blockIdx.x * FG;
    const int b0 = (blockIdx.y * WAVES + wave) * BPW;

    const int f  = f0 + (lane >> 3);
    const int e4 = lane & 7;

    // ---- bulk-stage x tile: lane l loads x[b0+l][f0..f0+8) (32 B burst) ----
    {
        const float* xsrc = x + (size_t)(b0 + lane) * F_ + f0;
        v4f xa = *(const v4f*)xsrc;
        v4f xb = *(const v4f*)(xsrc + 4);
        *(v4f*)&xs[wave][lane * FG]     = xa;
        *(v4f*)&xs[wave][lane * FG + 4] = xb;
    }

    // ---- per-lane weight fragments in registers ----
    float w1v[H_], b1v[H_];
    {
        const v4f* p1 = (const v4f*)(W1 + f * H_);
        const v4f* p2 = (const v4f*)(b1 + f * H_);
#pragma unroll
        for (int q = 0; q < 4; ++q) {
            v4f a = p1[q], c = p2[q];
            w1v[q*4+0]=a.x; w1v[q*4+1]=a.y; w1v[q*4+2]=a.z; w1v[q*4+3]=a.w;
            b1v[q*4+0]=c.x; b1v[q*4+1]=c.y; b1v[q*4+2]=c.z; b1v[q*4+3]=c.w;
        }
    }
    v4f w2v[H_];
#pragma unroll
    for (int j = 0; j < H_; ++j)
        w2v[j] = *(const v4f*)(W2 + (f * H_ + j) * E_ + e4 * 4);
    const v4f b2v = *(const v4f*)(b2 + f * E_ + e4 * 4);

    // ---- streaming loop over b: LDS broadcast read + nt store only ----
    const float* xw = &xs[wave][0];
    const int fsel = lane >> 3;
    v4f* op = (v4f*)out + (size_t)b0 * (F_ * E_ / 4)
            + f0 * (E_ / 4) + lane;

    float xv_next = xw[fsel];
#pragma unroll 2
    for (int i = 0; i < BPW; ++i) {
        const float xv = xv_next;
        if (i + 1 < BPW) xv_next = xw[(i + 1) * FG + fsel];

        v4f acc = b2v;
#pragma unroll
        for (int j = 0; j < H_; ++j) {
            const float hj = fmaxf(fmaf(xv, w1v[j], b1v[j]), 0.0f);
            acc.x = fmaf(hj, w2v[j].x, acc.x);
            acc.y = fmaf(hj, w2v[j].y, acc.y);
            acc.z = fmaf(hj, w2v[j].z, acc.z);
            acc.w = fmaf(hj, w2v[j].w, acc.w);
        }
        __builtin_nontemporal_store(acc, op + i * (F_ * E_ / 4));
    }
}

extern "C" void kernel_launch(void* const* d_in, const int* in_sizes, int n_in,
                              void* d_out, int out_size, void* d_ws, size_t ws_size,
                              hipStream_t stream) {
    const float* x  = (const float*)d_in[0];
    const float* W1 = (const float*)d_in[1];
    const float* b1 = (const float*)d_in[2];
    const float* W2 = (const float*)d_in[3];
    const float* b2 = (const float*)d_in[4];
    float* out = (float*)d_out;

    const int B = in_sizes[0] / F_;                 // 16384
    dim3 grid(F_ / FG, B / (BPW * WAVES));          // (16, 64)
    nfe_kernel<<<grid, NTHREADS, 0, stream>>>(x, W1, b1, W2, b2, out);
}

// Round 5
// 61.580 us; speedup vs baseline: 1.0390x; 1.0390x over previous
//
#include <hip/hip_runtime.h>

#define F_    128
#define H_    16
#define E_    32
#define FG    8     // features per wave
#define BPW   64    // b rows per wave
#define WAVES 4
#define NTHREADS 256
#define BCH   8     // b's per register chunk
#define NCH   (BPW / BCH)   // 8 chunks

typedef float v4f __attribute__((ext_vector_type(4)));

// Wave owns 8 features x 64 b's. Lane l -> (f = f0 + l>>3, e4 = l&7); per b
// one coalesced 1 KB nt wave-store. x is staged in REGISTERS in 8-b chunks,
// double-buffered (named arrays, statically indexed). Next chunk's loads are
// issued BEFORE the current chunk's stores, so the compiler's s_waitcnt for
// the loads is vmcnt(~16) — the previous chunk's 8 stores remain in flight
// (vmcnt is FIFO: stores issued AFTER the awaited loads need not drain).
// This keeps an 8-deep store pipeline per wave instead of R2's 1-deep.
__global__ __launch_bounds__(NTHREADS, 3)
void nfe_kernel(const float* __restrict__ x,
                const float* __restrict__ W1,
                const float* __restrict__ b1,
                const float* __restrict__ W2,
                const float* __restrict__ b2,
                float* __restrict__ out)
{
    const int tid  = threadIdx.x;
    const int wave = tid >> 6;
    const int lane = tid & 63;

    const int f0 = blockIdx.x * FG;
    const int b0 = (blockIdx.y * WAVES + wave) * BPW;

    const int f  = f0 + (lane >> 3);
    const int e4 = lane & 7;

    // ---- per-lane weight fragments in registers ----
    float w1v[H_], b1v[H_];
    {
        const v4f* p1 = (const v4f*)(W1 + f * H_);
        const v4f* p2 = (const v4f*)(b1 + f * H_);
#pragma unroll
        for (int q = 0; q < 4; ++q) {
            v4f a = p1[q], c = p2[q];
            w1v[q*4+0]=a.x; w1v[q*4+1]=a.y; w1v[q*4+2]=a.z; w1v[q*4+3]=a.w;
            b1v[q*4+0]=c.x; b1v[q*4+1]=c.y; b1v[q*4+2]=c.z; b1v[q*4+3]=c.w;
        }
    }
    v4f w2v[H_];
#pragma unroll
    for (int j = 0; j < H_; ++j)
        w2v[j] = *(const v4f*)(W2 + (f * H_ + j) * E_ + e4 * 4);
    const v4f b2v = *(const v4f*)(b2 + f * E_ + e4 * 4);

    const float* xp = x + (size_t)b0 * F_ + f;
    v4f* op = (v4f*)out + (size_t)b0 * (F_ * E_ / 4)
            + f0 * (E_ / 4) + lane;
    const int ostride = F_ * E_ / 4;   // v4f per b-row

    float xA[BCH], xB[BCH];
#pragma unroll
    for (int k = 0; k < BCH; ++k) xA[k] = xp[k * F_];

#define NFE_BODY(XCUR, XNXT, C)                                              \
    do {                                                                     \
        if ((C) + 1 < NCH) {                                                 \
            _Pragma("unroll")                                                \
            for (int k = 0; k < BCH; ++k)                                    \
                XNXT[k] = xp[(((C) + 1) * BCH + k) * F_];                    \
        }                                                                    \
        __builtin_amdgcn_sched_barrier(0);                                   \
        _Pragma("unroll")                                                    \
        for (int k = 0; k < BCH; ++k) {                                      \
            const float xv = XCUR[k];                                        \
            v4f acc = b2v;                                                   \
            _Pragma("unroll")                                                \
            for (int j = 0; j < H_; ++j) {                                   \
                const float hj = fmaxf(fmaf(xv, w1v[j], b1v[j]), 0.0f);      \
                acc.x = fmaf(hj, w2v[j].x, acc.x);                           \
                acc.y = fmaf(hj, w2v[j].y, acc.y);                           \
                acc.z = fmaf(hj, w2v[j].z, acc.z);                           \
                acc.w = fmaf(hj, w2v[j].w, acc.w);                           \
            }                                                                \
            __builtin_nontemporal_store(acc, op + ((C) * BCH + k) * ostride);\
        }                                                                    \
    } while (0)

#pragma unroll
    for (int c = 0; c < NCH; c += 2) {
        NFE_BODY(xA, xB, c);
        NFE_BODY(xB, xA, c + 1);
    }
#undef NFE_BODY
}

extern "C" void kernel_launch(void* const* d_in, const int* in_sizes, int n_in,
                              void* d_out, int out_size, void* d_ws, size_t ws_size,
                              hipStream_t stream) {
    const float* x  = (const float*)d_in[0];
    const float* W1 = (const float*)d_in[1];
    const float* b1 = (const float*)d_in[2];
    const float* W2 = (const float*)d_in[3];
    const float* b2 = (const float*)d_in[4];
    float* out = (float*)d_out;

    const int B = in_sizes[0] / F_;                 // 16384
    dim3 grid(F_ / FG, B / (BPW * WAVES));          // (16, 64)
    nfe_kernel<<<grid, NTHREADS, 0, stream>>>(x, W1, b1, W2, b2, out);
}